// Round 7
// baseline (148.937 us; speedup 1.0000x reference)
//
#include <hip/hip_runtime.h>

#define BB 2
#define NN 2048
#define CQc 256
#define CHc 256
#define HHc 8
#define DDc 32

typedef __bf16 bf16_t;
typedef bf16_t bf16x8 __attribute__((ext_vector_type(8)));
typedef float f32x4 __attribute__((ext_vector_type(4)));

#define LOG2E 1.4426950408889634f

static __device__ __forceinline__ unsigned short f2bf(float f) {
  union { float f; unsigned u; } a; a.f = f;
  unsigned r = a.u + 0x7FFFu + ((a.u >> 16) & 1u);
  return (unsigned short)(r >> 16);
}

static __device__ __forceinline__ bf16x8 ldb8(const unsigned short* p) {
  return *reinterpret_cast<const bf16x8*>(p);
}

// ---------------- kernel 0: weights -> bf16, transposed [n][k] ----------------
__global__ void prep_w(const float* __restrict__ Wq, const float* __restrict__ Wk,
                       const float* __restrict__ Wv, const float* __restrict__ Wg,
                       const float* __restrict__ Wo, unsigned short* __restrict__ wt) {
  int gid = blockIdx.x * 256 + threadIdx.x;  // 0 .. 5*65536-1
  int w = gid >> 16, r = gid & 65535;
  int n = r >> 8, k = r & 255;
  const float* W = (w == 0) ? Wq : (w == 1) ? Wk : (w == 2) ? Wv : (w == 3) ? Wg : Wo;
  wt[gid] = f2bf(W[k * 256 + n]);
}

// ---------------- kernel 1: Q/K/V projections (gate moved to outp_k) ----------
// q is pre-scaled by (1/sqrt(D)) * log2(e) so attention softmax can use exp2.
__global__ __launch_bounds__(256) void proj_k(
    const float* __restrict__ X, const float* __restrict__ bq,
    const unsigned short* __restrict__ wt,
    unsigned short* __restrict__ q_ws, unsigned short* __restrict__ k_ws,
    unsigned short* __restrict__ vt_ws) {
  const int tid = threadIdx.x;
  const int wave = tid >> 6, l = tid & 63, g = l >> 4, l15 = l & 15;
  const int mrow = blockIdx.x * 64 + wave * 16 + l15;  // A-fragment row
  const int widx = blockIdx.y >> 2;                    // 0=Wq 1=Wk 2=Wv
  const int nin0 = (blockIdx.y & 3) * 64;              // col within weight
  const unsigned short* W = wt + widx * 65536;

  f32x4 acc[4];
#pragma unroll
  for (int st = 0; st < 4; ++st) acc[st] = f32x4{0.f, 0.f, 0.f, 0.f};

#pragma unroll
  for (int kk0 = 0; kk0 < 256; kk0 += 32) {
    const float* xp = X + mrow * 256 + kk0 + 8 * g;
    f32x4 x0 = *reinterpret_cast<const f32x4*>(xp);
    f32x4 x1 = *reinterpret_cast<const f32x4*>(xp + 4);
    union { unsigned short u[8]; bf16x8 v; } av;
#pragma unroll
    for (int e = 0; e < 4; ++e) { av.u[e] = f2bf(x0[e]); av.u[4 + e] = f2bf(x1[e]); }
#pragma unroll
    for (int st = 0; st < 4; ++st) {
      bf16x8 bv = ldb8(W + (nin0 + st * 16 + l15) * 256 + kk0 + 8 * g);
      acc[st] = __builtin_amdgcn_mfma_f32_16x16x32_bf16(av.v, bv, acc[st], 0, 0, 0);
    }
  }

  const int mb = blockIdx.x * 64 + wave * 16 + 4 * g;  // D rows = 4g+j
#pragma unroll
  for (int st = 0; st < 4; ++st) {
    const int n = nin0 + st * 16 + l15;
    const int h = n >> 5, d = n & 31;
#pragma unroll
    for (int j = 0; j < 4; ++j) {
      const int m = mb + j;
      const int b = m >> 11, t = m & 2047;
      float val = acc[st][j];
      if (widx == 0) {
        q_ws[((b * 8 + h) * 2048 + t) * 32 + d] =
            f2bf((val + bq[n]) * (0.17677669529663687f * LOG2E));
      } else if (widx == 1) {
        k_ws[((b * 8 + h) * 2048 + t) * 32 + d] = f2bf(val);
      } else {
        vt_ws[((b * 8 + h) * 32 + d) * 2048 + t] = f2bf(val);  // V transposed [b,h,d,n]
      }
    }
  }
}

// ---------------- kernel 2: flash attention, contiguous-row span staging -------
// grid: 512 blocks (16 bh * 32 q-tiles of 64). 4 INDEPENDENT waves (no barriers,
// no merge), wave owns 16 q-rows, walks all 2048 keys (r5's proven pipeline).
// Change vs r5: bias staged per wave as a [16 rows x 256 cols] fp32 span (dbuf,
// 16 KB each): each global_load_lds reads 1 KB CONTIGUOUS from ONE bias row
// (64 lanes x 16 B) -> 4x DRAM run length per row-stream touch vs r5's 256 B.
// Span-top vmcnt(0) is near-free (last stage instrs issued ~1 tile earlier).
// In-tile order: K/V loads first, THEN next-span stage instrs, so compiler's
// positional K/V waits leave the newest stages in flight (r5-proven).
__global__ __launch_bounds__(256) void attn_k(
    const unsigned short* __restrict__ q_ws, const unsigned short* __restrict__ k_ws,
    const unsigned short* __restrict__ vt_ws, const float* __restrict__ bias,
    unsigned short* __restrict__ o_ws) {
  __shared__ float sbias[4][2][16][256];          // 128 KB: [wave][buf][row][col]
  __shared__ unsigned short plds[4][16 * 72];     // 9 KB per-wave P buffers
  const int tid = threadIdx.x;
  const int wave = tid >> 6, l = tid & 63, g = l >> 4, l15 = l & 15;
  const int bh = blockIdx.x >> 5, qt = blockIdx.x & 31;
  const int qr0 = qt * 64 + wave * 16;
  const int kvbase = bh * 2048;
  unsigned short* pw = plds[wave];

  const bf16x8 qa = ldb8(q_ws + (size_t)(kvbase + qr0 + l15) * 32 + 8 * g);
  const unsigned short* kbase = k_ws + (size_t)kvbase * 32 + 8 * g + l15 * 32;
  const unsigned short* vbase = vt_ws + (size_t)(bh * 32 + l15) * 2048 + 8 * g;
  // per-lane staging source: lane l reads 16 B at float-offset l*4 within a row
  const float* bsrc = bias + ((size_t)bh << 22) + (size_t)qr0 * 2048 + l * 4;

  // stage rows r0..r0+3 of span sp into buffer buf (4 instrs, 1 KB contiguous each)
#define STG(buf, sp, r0)                                                         \
  {                                                                              \
    _Pragma("unroll") for (int r = (r0); r < (r0) + 4; ++r)                      \
        __builtin_amdgcn_global_load_lds(                                        \
            (const __attribute__((address_space(1))) void*)(                     \
                bsrc + (size_t)r * 2048 + (sp) * 256),                           \
            (__attribute__((address_space(3))) void*)(&sbias[wave][buf][r][0]),  \
            16, 0, 0);                                                           \
  }

  float mr[4], lr[4];
  f32x4 oacc[2];
#pragma unroll
  for (int j = 0; j < 4; ++j) { mr[j] = -1e30f; lr[j] = 0.0f; }
  oacc[0] = f32x4{0.f, 0.f, 0.f, 0.f};
  oacc[1] = f32x4{0.f, 0.f, 0.f, 0.f};

  // prologue: stage span 0 into buf 0 (16 instrs)
  STG(0, 0, 0); STG(0, 0, 4); STG(0, 0, 8); STG(0, 0, 12);

#pragma unroll 1
  for (int sp = 0; sp < 8; ++sp) {
    const int buf = sp & 1;
    // all outstanding vmem = stage(sp); drain it (near-free: issued >=1 tile ago)
    asm volatile("s_waitcnt vmcnt(0)" ::: "memory");
    __builtin_amdgcn_sched_barrier(0);
#pragma unroll
    for (int t = 0; t < 4; ++t) {
      const int k0 = sp * 256 + t * 64;
      // K/V loads first (older than stage -> compiler waits leave stages in flight)
      bf16x8 kb[4];
#pragma unroll
      for (int st = 0; st < 4; ++st) kb[st] = ldb8(kbase + (size_t)(k0 + st * 16) * 32);
      bf16x8 vb[2][2];
#pragma unroll
      for (int dst = 0; dst < 2; ++dst)
#pragma unroll
        for (int kc = 0; kc < 2; ++kc)
          vb[dst][kc] = ldb8(vbase + (size_t)dst * 16 * 2048 + k0 + kc * 32);
      // stage 4 rows of next span into the other buffer
      if (sp < 7) { STG(buf ^ 1, sp + 1, 4 * t); }
      // bias C-fragments from resident span
      f32x4 cfr[4];
#pragma unroll
      for (int st = 0; st < 4; ++st)
#pragma unroll
        for (int j = 0; j < 4; ++j)
          cfr[st][j] = sbias[wave][buf][4 * g + j][t * 64 + st * 16 + l15] * LOG2E;
      // S = QK^T + bias (C-operand), base-2 domain
      f32x4 s[4];
#pragma unroll
      for (int st = 0; st < 4; ++st)
        s[st] = __builtin_amdgcn_mfma_f32_16x16x32_bf16(qa, kb[st], cfr[st], 0, 0, 0);
      // online softmax per row (row = 4g+j)
#pragma unroll
      for (int j = 0; j < 4; ++j) {
        float mx = fmaxf(fmaxf(s[0][j], s[1][j]), fmaxf(s[2][j], s[3][j]));
        mx = fmaxf(mx, __shfl_xor(mx, 1));
        mx = fmaxf(mx, __shfl_xor(mx, 2));
        mx = fmaxf(mx, __shfl_xor(mx, 4));
        mx = fmaxf(mx, __shfl_xor(mx, 8));
        const float mn = fmaxf(mr[j], mx);
        const float sc = __builtin_amdgcn_exp2f(mr[j] - mn);
        mr[j] = mn;
        float rs = 0.f;
#pragma unroll
        for (int st = 0; st < 4; ++st) {
          float e = __builtin_amdgcn_exp2f(s[st][j] - mn);
          s[st][j] = e;
          rs += e;
        }
        rs += __shfl_xor(rs, 1);
        rs += __shfl_xor(rs, 2);
        rs += __shfl_xor(rs, 4);
        rs += __shfl_xor(rs, 8);
        lr[j] = lr[j] * sc + rs;
        oacc[0][j] *= sc;
        oacc[1][j] *= sc;
      }
      // P -> LDS transpose (per-wave buffer, pitch 72), then PV
#pragma unroll
      for (int st = 0; st < 4; ++st)
#pragma unroll
        for (int j = 0; j < 4; ++j)
          pw[(4 * g + j) * 72 + st * 16 + l15] = f2bf(s[st][j]);
#pragma unroll
      for (int kc = 0; kc < 2; ++kc) {
        bf16x8 pa = ldb8(pw + l15 * 72 + kc * 32 + 8 * g);
        oacc[0] = __builtin_amdgcn_mfma_f32_16x16x32_bf16(pa, vb[0][kc], oacc[0], 0, 0, 0);
        oacc[1] = __builtin_amdgcn_mfma_f32_16x16x32_bf16(pa, vb[1][kc], oacc[1], 0, 0, 0);
      }
    }
  }
#undef STG

  const int b = bh >> 3, h = bh & 7;
#pragma unroll
  for (int dst = 0; dst < 2; ++dst)
#pragma unroll
    for (int j = 0; j < 4; ++j) {
      const int q = qr0 + 4 * g + j;
      const float val = oacc[dst][j] / lr[j];
      o_ws[((size_t)(b * 2048 + q)) * 256 + h * 32 + dst * 16 + l15] = f2bf(val);
    }
}

// ---------------- kernel 3: out = sigmoid(x@Wg + bg + gbias) * (o@Wout + bout) -
__global__ __launch_bounds__(256) void outp_k(
    const unsigned short* __restrict__ o_ws, const unsigned short* __restrict__ wt,
    const float* __restrict__ X, const float* __restrict__ bout,
    const float* __restrict__ bg, const float* __restrict__ gbias,
    float* __restrict__ out) {
  const int tid = threadIdx.x;
  const int wave = tid >> 6, l = tid & 63, g = l >> 4, l15 = l & 15;
  const int m0 = blockIdx.x * 64 + wave * 16;
  const int c0 = blockIdx.y * 64;
  const unsigned short* wgt = wt + 3 * 65536;  // Wg^T bf16
  const unsigned short* wot = wt + 4 * 65536;  // Wout^T bf16
  f32x4 acco[4], accg[4];
#pragma unroll
  for (int st = 0; st < 4; ++st) {
    acco[st] = f32x4{0.f, 0.f, 0.f, 0.f};
    accg[st] = f32x4{0.f, 0.f, 0.f, 0.f};
  }
#pragma unroll
  for (int kk0 = 0; kk0 < 256; kk0 += 32) {
    bf16x8 a_o = ldb8(o_ws + (m0 + l15) * 256 + kk0 + 8 * g);
    const float* xp = X + (m0 + l15) * 256 + kk0 + 8 * g;
    f32x4 x0 = *reinterpret_cast<const f32x4*>(xp);
    f32x4 x1 = *reinterpret_cast<const f32x4*>(xp + 4);
    union { unsigned short u[8]; bf16x8 v; } av;
#pragma unroll
    for (int e = 0; e < 4; ++e) { av.u[e] = f2bf(x0[e]); av.u[4 + e] = f2bf(x1[e]); }
#pragma unroll
    for (int st = 0; st < 4; ++st) {
      bf16x8 bo = ldb8(wot + (c0 + st * 16 + l15) * 256 + kk0 + 8 * g);
      acco[st] = __builtin_amdgcn_mfma_f32_16x16x32_bf16(a_o, bo, acco[st], 0, 0, 0);
      bf16x8 bgf = ldb8(wgt + (c0 + st * 16 + l15) * 256 + kk0 + 8 * g);
      accg[st] = __builtin_amdgcn_mfma_f32_16x16x32_bf16(av.v, bgf, accg[st], 0, 0, 0);
    }
  }
  const int mb = m0 + 4 * g;
#pragma unroll
  for (int st = 0; st < 4; ++st) {
    const int n = c0 + st * 16 + l15;
#pragma unroll
    for (int j = 0; j < 4; ++j) {
      const int m = mb + j;
      const float z = accg[st][j] + bg[n] + gbias[n];
      const float gate = 1.0f / (1.0f + __expf(-z));
      out[m * 256 + n] = gate * (acco[st][j] + bout[n]);
    }
  }
}

extern "C" void kernel_launch(void* const* d_in, const int* in_sizes, int n_in,
                              void* d_out, int out_size, void* d_ws, size_t ws_size,
                              hipStream_t stream) {
  const float* q_x   = (const float*)d_in[0];
  const float* bias  = (const float*)d_in[1];
  const float* Wq    = (const float*)d_in[2];
  const float* bq    = (const float*)d_in[3];
  const float* Wk    = (const float*)d_in[4];
  const float* Wv    = (const float*)d_in[5];
  const float* Wout  = (const float*)d_in[6];
  const float* bout  = (const float*)d_in[7];
  const float* Wg    = (const float*)d_in[8];
  const float* bg    = (const float*)d_in[9];
  const float* gbias = (const float*)d_in[10];
  float* out = (float*)d_out;

  char* ws = (char*)d_ws;
  unsigned short* wt    = (unsigned short*)(ws);                        // 655,360 B
  unsigned short* q_ws  = (unsigned short*)(ws + 655360);               // 2 MB
  unsigned short* k_ws  = (unsigned short*)(ws + 655360 + 2097152);     // 2 MB
  unsigned short* vt_ws = (unsigned short*)(ws + 655360 + 2 * 2097152); // 2 MB
  unsigned short* o_ws  = (unsigned short*)(ws + 655360 + 3 * 2097152); // 2 MB

  prep_w<<<1280, 256, 0, stream>>>(Wq, Wk, Wv, Wg, Wout, wt);
  proj_k<<<dim3(64, 12), 256, 0, stream>>>(q_x, bq, wt, q_ws, k_ws, vt_ws);
  attn_k<<<512, 256, 0, stream>>>(q_ws, k_ws, vt_ws, bias, o_ws);
  outp_k<<<dim3(64, 4), 256, 0, stream>>>(o_ws, wt, q_x, bout, bg, gbias, out);
}

// Round 8
// 112.004 us; speedup vs baseline: 1.3297x; 1.3297x over previous
//
#include <hip/hip_runtime.h>

typedef __bf16 bf16_t;
typedef bf16_t bf16x8 __attribute__((ext_vector_type(8)));
typedef float f32x4 __attribute__((ext_vector_type(4)));
typedef unsigned short ushort8 __attribute__((ext_vector_type(8)));

#define LOG2E 1.4426950408889634f

static __device__ __forceinline__ unsigned short f2bf(float f) {
  union { float f; unsigned u; } a; a.f = f;
  unsigned r = a.u + 0x7FFFu + ((a.u >> 16) & 1u);
  return (unsigned short)(r >> 16);
}

static __device__ __forceinline__ bf16x8 ldb8(const unsigned short* p) {
  return *reinterpret_cast<const bf16x8*>(p);
}

// ---------- kernel 0: coalesced weight transpose->bf16 + X->bf16 cast ----------
// blocks 0..319: 32x32 LDS-tiled transpose of the 5 weights (coalesced R+W).
// blocks 320+  : straight X cast, f32x4 -> 4xbf16 per thread.
__global__ __launch_bounds__(256) void prep_k(
    const float* __restrict__ Wq, const float* __restrict__ Wk,
    const float* __restrict__ Wv, const float* __restrict__ Wg,
    const float* __restrict__ Wo, const float* __restrict__ X,
    unsigned short* __restrict__ wt, unsigned short* __restrict__ xb) {
  const int bid = blockIdx.x;
  if (bid < 320) {
    __shared__ float t[32][33];
    const int w = bid >> 6, tile = bid & 63;
    const int r0 = (tile >> 3) * 32, c0 = (tile & 7) * 32;
    const float* W = (w == 0) ? Wq : (w == 1) ? Wk : (w == 2) ? Wv : (w == 3) ? Wg : Wo;
    const int x = threadIdx.x & 31, y = threadIdx.x >> 5;  // y = 0..7
#pragma unroll
    for (int yy = 0; yy < 32; yy += 8) t[y + yy][x] = W[(r0 + y + yy) * 256 + c0 + x];
    __syncthreads();
#pragma unroll
    for (int yy = 0; yy < 32; yy += 8)
      wt[w * 65536 + (c0 + y + yy) * 256 + r0 + x] = f2bf(t[x][y + yy]);
  } else {
    const int i = (bid - 320) * 1024 + threadIdx.x * 4;  // 1024 blocks cover 1M elems
    const f32x4 v = *reinterpret_cast<const f32x4*>(X + i);
    unsigned short o[4];
#pragma unroll
    for (int e = 0; e < 4; ++e) o[e] = f2bf(v[e]);
    *reinterpret_cast<unsigned long long*>(xb + i) = *reinterpret_cast<unsigned long long*>(o);
  }
}

// ---------------- kernel 1: Q/K/V projections from bf16 X ----------------
// q is pre-scaled by (1/sqrt(D)) * log2(e) so attention softmax can use exp2.
// V epilogue: 64x64 tile transposed through LDS -> coalesced 16B stores.
__global__ __launch_bounds__(256) void proj_k(
    const unsigned short* __restrict__ xb, const float* __restrict__ bq,
    const unsigned short* __restrict__ wt,
    unsigned short* __restrict__ q_ws, unsigned short* __restrict__ k_ws,
    unsigned short* __restrict__ vt_ws) {
  __shared__ unsigned short vtile[64][72];  // [n][m], padded
  const int tid = threadIdx.x;
  const int wave = tid >> 6, l = tid & 63, g = l >> 4, l15 = l & 15;
  const int mrow = blockIdx.x * 64 + wave * 16 + l15;  // A-fragment row
  const int widx = blockIdx.y >> 2;                    // 0=Wq 1=Wk 2=Wv
  const int nin0 = (blockIdx.y & 3) * 64;              // col within weight
  const unsigned short* W = wt + widx * 65536;

  f32x4 acc[4];
#pragma unroll
  for (int st = 0; st < 4; ++st) acc[st] = f32x4{0.f, 0.f, 0.f, 0.f};

#pragma unroll
  for (int kk0 = 0; kk0 < 256; kk0 += 32) {
    const bf16x8 av = ldb8(xb + mrow * 256 + kk0 + 8 * g);
#pragma unroll
    for (int st = 0; st < 4; ++st) {
      bf16x8 bv = ldb8(W + (nin0 + st * 16 + l15) * 256 + kk0 + 8 * g);
      acc[st] = __builtin_amdgcn_mfma_f32_16x16x32_bf16(av, bv, acc[st], 0, 0, 0);
    }
  }

  const int mb = blockIdx.x * 64 + wave * 16 + 4 * g;  // D rows = 4g+j
  if (widx == 2) {
    // V: stage transposed tile in LDS, then cooperative coalesced write-out
#pragma unroll
    for (int st = 0; st < 4; ++st)
#pragma unroll
      for (int j = 0; j < 4; ++j)
        vtile[st * 16 + l15][wave * 16 + 4 * g + j] = f2bf(acc[st][j]);
    __syncthreads();
    const int b = (blockIdx.x * 64) >> 11;
    const int t0 = (blockIdx.x * 64) & 2047;
#pragma unroll
    for (int it = tid; it < 512; it += 256) {  // 64 rows x 8 col-chunks of 8
      const int r = it >> 3, cseg = (it & 7) * 8;
      const int n = nin0 + r;
      *reinterpret_cast<ushort8*>(vt_ws + (size_t)((b * 8 + (n >> 5)) * 32 + (n & 31)) * 2048 +
                                  t0 + cseg) = *reinterpret_cast<const ushort8*>(&vtile[r][cseg]);
    }
  } else {
#pragma unroll
    for (int st = 0; st < 4; ++st) {
      const int n = nin0 + st * 16 + l15;
      const int h = n >> 5, d = n & 31;
#pragma unroll
      for (int j = 0; j < 4; ++j) {
        const int m = mb + j;
        const int b = m >> 11, t = m & 2047;
        if (widx == 0) {
          q_ws[((b * 8 + h) * 2048 + t) * 32 + d] =
              f2bf((acc[st][j] + bq[n]) * (0.17677669529663687f * LOG2E));
        } else {
          k_ws[((b * 8 + h) * 2048 + t) * 32 + d] = f2bf(acc[st][j]);
        }
      }
    }
  }
}

// ---------------- kernel 2: flash attention, LDS-staged bias, depth-2 pipeline ----
// (byte-exact r5 structure: proven 69.5 us, 3.86 TB/s bias)
__global__ __launch_bounds__(256) void attn_k(
    const unsigned short* __restrict__ q_ws, const unsigned short* __restrict__ k_ws,
    const unsigned short* __restrict__ vt_ws, const float* __restrict__ bias,
    unsigned short* __restrict__ o_ws) {
  __shared__ float sbias[4 * 3 * 1024];         // [wave][3 bufs][16*64] = 48 KB
  __shared__ unsigned short plds[4 * 16 * 72];  // per-wave P buffer, pitch 72 bf16
  const int tid = threadIdx.x;
  const int wave = tid >> 6, l = tid & 63, g = l >> 4, l15 = l & 15;
  const int bh = blockIdx.x >> 5, qt = blockIdx.x & 31;
  const int qr0 = qt * 64 + wave * 16;
  const int kvbase = bh * 2048;
  unsigned short* pw = plds + wave * (16 * 72);
  float* sb = sbias + wave * 3072;

  const bf16x8 qa = ldb8(q_ws + (size_t)(kvbase + qr0 + l15) * 32 + 8 * g);
  const unsigned short* kbase = k_ws + (size_t)kvbase * 32 + 8 * g + l15 * 32;
  const unsigned short* vbase = vt_ws + (size_t)(bh * 32 + l15) * 2048 + 8 * g;
  // per-lane staging source: lane l covers row (l>>4) of each 4-row group, 16B at col (l&15)*4
  const float* bsrc = bias + ((size_t)bh << 22) + (size_t)(qr0 + (l >> 4)) * 2048 + (l & 15) * 4;

  // stage tile with key-offset k0 into LDS buffer bidx (4 x 1KB instrs)
  auto stage = [&](int bidx, int k0) {
    float* dst = sb + bidx * 1024;
#pragma unroll
    for (int qq = 0; qq < 4; ++qq)
      __builtin_amdgcn_global_load_lds(
          (const __attribute__((address_space(1))) void*)(bsrc + (size_t)qq * 8192 + k0),
          (__attribute__((address_space(3))) void*)(dst + qq * 256), 16, 0, 0);
  };

  float mr[4], lr[4];
  f32x4 oacc[2];
#pragma unroll
  for (int j = 0; j < 4; ++j) { mr[j] = -1e30f; lr[j] = 0.0f; }
  oacc[0] = f32x4{0.f, 0.f, 0.f, 0.f};
  oacc[1] = f32x4{0.f, 0.f, 0.f, 0.f};

  stage(0, 0);
  stage(1, 64);
  int cb = 0;  // buffer holding tile kt
#pragma unroll 1
  for (int kt = 0; kt < 32; ++kt) {
    const int k0 = kt * 64;
    // wait for stage(kt); stage(kt+1)'s 4 loads may stay in flight
    if (kt < 31) {
      asm volatile("s_waitcnt vmcnt(4)" ::: "memory");
    } else {
      asm volatile("s_waitcnt vmcnt(0)" ::: "memory");
    }
    __builtin_amdgcn_sched_barrier(0);
    // bias fragments (C-operand layout) from LDS buffer cb
    f32x4 cfr[4];
    const float* sbc = sb + cb * 1024 + l15;
#pragma unroll
    for (int st = 0; st < 4; ++st)
#pragma unroll
      for (int j = 0; j < 4; ++j)
        cfr[st][j] = sbc[(4 * g + j) * 64 + st * 16] * LOG2E;

    // K/V fragment loads for this tile (issued before next staging)
    bf16x8 kb[4];
#pragma unroll
    for (int st = 0; st < 4; ++st) kb[st] = ldb8(kbase + (size_t)(k0 + st * 16) * 32);
    bf16x8 vb[2][2];
#pragma unroll
    for (int dst = 0; dst < 2; ++dst)
#pragma unroll
      for (int kc = 0; kc < 2; ++kc)
        vb[dst][kc] = ldb8(vbase + (size_t)dst * 16 * 2048 + k0 + kc * 32);

    // issue stage(kt+2) into the buffer freed at kt-1
    int nb = cb + 2; if (nb >= 3) nb -= 3;
    if (kt < 30) stage(nb, k0 + 128);

    // S = QK^T + bias (bias as MFMA C-operand), base-2 domain
    f32x4 s[4];
#pragma unroll
    for (int st = 0; st < 4; ++st)
      s[st] = __builtin_amdgcn_mfma_f32_16x16x32_bf16(qa, kb[st], cfr[st], 0, 0, 0);

    // online softmax per row (row = 4g+j)
#pragma unroll
    for (int j = 0; j < 4; ++j) {
      float mx = fmaxf(fmaxf(s[0][j], s[1][j]), fmaxf(s[2][j], s[3][j]));
      mx = fmaxf(mx, __shfl_xor(mx, 1));
      mx = fmaxf(mx, __shfl_xor(mx, 2));
      mx = fmaxf(mx, __shfl_xor(mx, 4));
      mx = fmaxf(mx, __shfl_xor(mx, 8));
      const float mn = fmaxf(mr[j], mx);
      const float sc = __builtin_amdgcn_exp2f(mr[j] - mn);
      mr[j] = mn;
      float rs = 0.f;
#pragma unroll
      for (int st = 0; st < 4; ++st) {
        float e = __builtin_amdgcn_exp2f(s[st][j] - mn);
        s[st][j] = e;
        rs += e;
      }
      rs += __shfl_xor(rs, 1);
      rs += __shfl_xor(rs, 2);
      rs += __shfl_xor(rs, 4);
      rs += __shfl_xor(rs, 8);
      lr[j] = lr[j] * sc + rs;
      oacc[0][j] *= sc;
      oacc[1][j] *= sc;
    }
    // P -> LDS (transpose to A-fragment layout); per-wave buffer, DS in-order
#pragma unroll
    for (int st = 0; st < 4; ++st)
#pragma unroll
      for (int j = 0; j < 4; ++j)
        pw[(4 * g + j) * 72 + st * 16 + l15] = f2bf(s[st][j]);
#pragma unroll
    for (int kc = 0; kc < 2; ++kc) {
      bf16x8 pa = ldb8(pw + l15 * 72 + kc * 32 + 8 * g);
      oacc[0] = __builtin_amdgcn_mfma_f32_16x16x32_bf16(pa, vb[0][kc], oacc[0], 0, 0, 0);
      oacc[1] = __builtin_amdgcn_mfma_f32_16x16x32_bf16(pa, vb[1][kc], oacc[1], 0, 0, 0);
    }
    cb = cb + 1; if (cb >= 3) cb -= 3;
  }

  const int b = bh >> 3, h = bh & 7;
#pragma unroll
  for (int dst = 0; dst < 2; ++dst)
#pragma unroll
    for (int j = 0; j < 4; ++j) {
      const int q = qr0 + 4 * g + j;
      const float val = oacc[dst][j] / lr[j];
      o_ws[((size_t)(b * 2048 + q)) * 256 + h * 32 + dst * 16 + l15] = f2bf(val);
    }
}

// ---------------- kernel 3: out = sigmoid(x@Wg + bg + gbias) * (o@Wout + bout) -
__global__ __launch_bounds__(256) void outp_k(
    const unsigned short* __restrict__ o_ws, const unsigned short* __restrict__ wt,
    const unsigned short* __restrict__ xb, const float* __restrict__ bout,
    const float* __restrict__ bg, const float* __restrict__ gbias,
    float* __restrict__ out) {
  const int tid = threadIdx.x;
  const int wave = tid >> 6, l = tid & 63, g = l >> 4, l15 = l & 15;
  const int m0 = blockIdx.x * 64 + wave * 16;
  const int c0 = blockIdx.y * 64;
  const unsigned short* wgt = wt + 3 * 65536;  // Wg^T bf16
  const unsigned short* wot = wt + 4 * 65536;  // Wout^T bf16
  f32x4 acco[4], accg[4];
#pragma unroll
  for (int st = 0; st < 4; ++st) {
    acco[st] = f32x4{0.f, 0.f, 0.f, 0.f};
    accg[st] = f32x4{0.f, 0.f, 0.f, 0.f};
  }
#pragma unroll
  for (int kk0 = 0; kk0 < 256; kk0 += 32) {
    const bf16x8 a_o = ldb8(o_ws + (m0 + l15) * 256 + kk0 + 8 * g);
    const bf16x8 a_x = ldb8(xb + (m0 + l15) * 256 + kk0 + 8 * g);
#pragma unroll
    for (int st = 0; st < 4; ++st) {
      bf16x8 bo = ldb8(wot + (c0 + st * 16 + l15) * 256 + kk0 + 8 * g);
      acco[st] = __builtin_amdgcn_mfma_f32_16x16x32_bf16(a_o, bo, acco[st], 0, 0, 0);
      bf16x8 bgf = ldb8(wgt + (c0 + st * 16 + l15) * 256 + kk0 + 8 * g);
      accg[st] = __builtin_amdgcn_mfma_f32_16x16x32_bf16(a_x, bgf, accg[st], 0, 0, 0);
    }
  }
  const int mb = m0 + 4 * g;
#pragma unroll
  for (int st = 0; st < 4; ++st) {
    const int n = c0 + st * 16 + l15;
#pragma unroll
    for (int j = 0; j < 4; ++j) {
      const int m = mb + j;
      const float z = accg[st][j] + bg[n] + gbias[n];
      const float gate = 1.0f / (1.0f + __expf(-z));
      out[m * 256 + n] = gate * (acco[st][j] + bout[n]);
    }
  }
}

extern "C" void kernel_launch(void* const* d_in, const int* in_sizes, int n_in,
                              void* d_out, int out_size, void* d_ws, size_t ws_size,
                              hipStream_t stream) {
  const float* q_x   = (const float*)d_in[0];
  const float* bias  = (const float*)d_in[1];
  const float* Wq    = (const float*)d_in[2];
  const float* bq    = (const float*)d_in[3];
  const float* Wk    = (const float*)d_in[4];
  const float* Wv    = (const float*)d_in[5];
  const float* Wout  = (const float*)d_in[6];
  const float* bout  = (const float*)d_in[7];
  const float* Wg    = (const float*)d_in[8];
  const float* bg    = (const float*)d_in[9];
  const float* gbias = (const float*)d_in[10];
  float* out = (float*)d_out;

  char* ws = (char*)d_ws;
  unsigned short* wt    = (unsigned short*)(ws);                        // 655,360 B
  unsigned short* xb    = (unsigned short*)(ws + 655360);               // 2 MB (X bf16)
  unsigned short* q_ws  = (unsigned short*)(ws + 655360 + 2097152);     // 2 MB
  unsigned short* k_ws  = (unsigned short*)(ws + 655360 + 2 * 2097152); // 2 MB
  unsigned short* vt_ws = (unsigned short*)(ws + 655360 + 3 * 2097152); // 2 MB
  unsigned short* o_ws  = (unsigned short*)(ws + 655360 + 4 * 2097152); // 2 MB

  prep_k<<<1344, 256, 0, stream>>>(Wq, Wk, Wv, Wg, Wout, q_x, wt, xb);
  proj_k<<<dim3(64, 12), 256, 0, stream>>>(xb, bq, wt, q_ws, k_ws, vt_ws);
  attn_k<<<512, 256, 0, stream>>>(q_ws, k_ws, vt_ws, bias, o_ws);
  outp_k<<<dim3(64, 4), 256, 0, stream>>>(o_ws, wt, xb, bout, bg, gbias, out);
}